// Round 17
// baseline (297.235 us; speedup 1.0000x reference)
//
#include <hip/hip_runtime.h>

typedef unsigned short u16;
typedef __bf16 bf16x8 __attribute__((ext_vector_type(8)));
typedef float f32x4 __attribute__((ext_vector_type(4)));
typedef unsigned short u16x4 __attribute__((ext_vector_type(4)));

#define MFMA_B16(a, b, c) __builtin_amdgcn_mfma_f32_16x16x32_bf16((a), (b), (c), 0, 0, 0)

// ---------- helpers ----------
__device__ __forceinline__ u16 f2bf(float f) {
  unsigned int u = __float_as_uint(f);
  u += 0x7FFFu + ((u >> 16) & 1u);   // RNE
  return (u16)(u >> 16);
}

__device__ __forceinline__ u16x4 f4_to_bf4(float4 v) {
  u16x4 r;
  r[0] = f2bf(v.x); r[1] = f2bf(v.y); r[2] = f2bf(v.z); r[3] = f2bf(v.w);
  return r;
}

// async 16B/lane global->LDS (dest = wave-uniform base + lane*16)
__device__ __forceinline__ void gl_lds16(const u16* g, u16* l) {
  __builtin_amdgcn_global_load_lds(
      (const __attribute__((address_space(1))) void*)g,
      (__attribute__((address_space(3))) void*)l, 16, 0, 0);
}

// ---------- f32 -> bf16 converts ----------
__global__ __launch_bounds__(256) void cvt3(const float* __restrict__ a,
                                            const float* __restrict__ b,
                                            const float* __restrict__ c,
                                            u16* __restrict__ dst, int n4, int n) {
  int i = blockIdx.x * 256 + threadIdx.x;
  int stride = gridDim.x * 256;
  const float4* a4 = (const float4*)a;
  const float4* b4 = (const float4*)b;
  const float4* c4 = (const float4*)c;
  u16x4* d0 = (u16x4*)dst;
  u16x4* d1 = (u16x4*)(dst + (size_t)n);
  u16x4* d2 = (u16x4*)(dst + (size_t)2 * n);
  for (; i < n4; i += stride) {
    d0[i] = f4_to_bf4(a4[i]);
    d1[i] = f4_to_bf4(b4[i]);
    d2[i] = f4_to_bf4(c4[i]);
  }
}

__global__ __launch_bounds__(256) void cvtW(const float* __restrict__ a,
                                            const float* __restrict__ b,
                                            const float* __restrict__ c,
                                            const float* __restrict__ d,
                                            u16* __restrict__ dst, int n4, int n) {
  int i = blockIdx.x * 256 + threadIdx.x;
  int stride = gridDim.x * 256;
  const float4* a4 = (const float4*)a;
  const float4* b4 = (const float4*)b;
  const float4* c4 = (const float4*)c;
  const float4* d4 = (const float4*)d;
  u16x4* o0 = (u16x4*)dst;
  u16x4* o1 = (u16x4*)(dst + (size_t)n);
  u16x4* o2 = (u16x4*)(dst + (size_t)2 * n);
  u16x4* o3 = (u16x4*)(dst + (size_t)3 * n);
  for (; i < n4; i += stride) {
    o0[i] = f4_to_bf4(a4[i]);
    o1[i] = f4_to_bf4(b4[i]);
    o2[i] = f4_to_bf4(c4[i]);
    o3[i] = f4_to_bf4(d4[i]);
  }
}

// ---------- B-transposed bf16 GEMM v2: global_load_lds staging ----------
template <bool OUT_F32>
__device__ __forceinline__ void gemm_body(const u16* __restrict__ A,
                                          const u16* __restrict__ Bw,
                                          u16* __restrict__ Cb, float* __restrict__ Cf,
                                          const float* __restrict__ resid,
                                          int bm, int bn) {
  __shared__ __align__(16) u16 As[128 * 32];
  __shared__ __align__(16) u16 Bs[128 * 32];
  const int tid = threadIdx.x;
  const int wave = tid >> 6, lane = tid & 63;
  const int g = lane >> 4, l16 = lane & 15;
  const int wr = (wave >> 1) * 64, wc = (wave & 1) * 64;

  const int r0 = wave * 32 + (lane >> 2);
  const int r1 = r0 + 16;
  const int c0 = (((lane & 3) ^ ((r0 >> 1) & 3)) << 3);
  const int c1 = (((lane & 3) ^ ((r1 >> 1) & 3)) << 3);
  const u16* Ar0 = A + (size_t)(bm + r0) * 512 + c0;
  const u16* Ar1 = A + (size_t)(bm + r1) * 512 + c1;
  const u16* Br0 = Bw + (size_t)(bn + r0) * 512 + c0;
  const u16* Br1 = Bw + (size_t)(bn + r1) * 512 + c1;
  u16* Ad0 = As + (wave * 32) * 32;
  u16* Ad1 = As + (wave * 32 + 16) * 32;
  u16* Bd0 = Bs + (wave * 32) * 32;
  u16* Bd1 = Bs + (wave * 32 + 16) * 32;

  f32x4 acc[4][4] = {};
  for (int k0 = 0; k0 < 512; k0 += 32) {
    gl_lds16(Ar0 + k0, Ad0);
    gl_lds16(Ar1 + k0, Ad1);
    gl_lds16(Br0 + k0, Bd0);
    gl_lds16(Br1 + k0, Bd1);
    __syncthreads();
    bf16x8 af[4], bfr[4];
#pragma unroll
    for (int i = 0; i < 4; ++i) {
      const int ar = wr + i * 16 + l16;
      af[i] = *(const bf16x8*)((const char*)As + ar * 64 + ((g ^ ((ar >> 1) & 3)) << 4));
    }
#pragma unroll
    for (int j = 0; j < 4; ++j) {
      const int br = wc + j * 16 + l16;
      bfr[j] = *(const bf16x8*)((const char*)Bs + br * 64 + ((g ^ ((br >> 1) & 3)) << 4));
    }
#pragma unroll
    for (int i = 0; i < 4; ++i)
#pragma unroll
      for (int j = 0; j < 4; ++j)
        acc[i][j] = MFMA_B16(af[i], bfr[j], acc[i][j]);
    __syncthreads();
  }
#pragma unroll
  for (int i = 0; i < 4; ++i)
#pragma unroll
    for (int j = 0; j < 4; ++j)
#pragma unroll
      for (int r = 0; r < 4; ++r) {
        int row = bm + wr + i * 16 + g * 4 + r;
        int col = bn + wc + j * 16 + l16;
        if constexpr (OUT_F32)
          Cf[(size_t)row * 512 + col] = acc[i][j][r] + resid[(size_t)row * 512 + col];
        else
          Cb[(size_t)row * 512 + col] = f2bf(acc[i][j][r]);
      }
}

__global__ __launch_bounds__(256) void gemm_qkv(const u16* __restrict__ Xbf,
                                                const u16* __restrict__ Wbf,
                                                u16* __restrict__ QKVp) {
  int z = blockIdx.z;
  gemm_body<false>(Xbf + (size_t)z * 4194304, Wbf + (size_t)z * 262144,
                   QKVp + (size_t)z * 4194304, nullptr, nullptr,
                   blockIdx.x * 128, blockIdx.y * 128);
}

__global__ __launch_bounds__(256) void gemm_f32out(const u16* __restrict__ A,
                                                   const u16* __restrict__ Bw,
                                                   float* __restrict__ C,
                                                   const float* __restrict__ resid) {
  gemm_body<true>(A, Bw, nullptr, C, resid, blockIdx.x * 128, blockIdx.y * 128);
}

// ---------- V transpose: Vp[b][s][d] (bf16) -> Vt[b][d][s] (bf16) ----------
__global__ __launch_bounds__(256) void transpose_v(const u16* __restrict__ Vp,
                                                   u16* __restrict__ Vt) {
  __shared__ __align__(16) u16 t[64][72];
  const int b = blockIdx.z;
  const int s0 = blockIdx.x * 64, d0 = blockIdx.y * 64;
  const u16* in = Vp + (size_t)b * 2048 * 512;
  u16* outp = Vt + (size_t)b * 512 * 2048;
  const int tid = threadIdx.x;
  const int r = tid >> 2;
  const int c = (tid & 3) * 16;
  const uint4* src = (const uint4*)(in + (size_t)(s0 + r) * 512 + d0 + c);
  uint4 v0 = src[0], v1 = src[1];
  *(uint4*)(&t[r][c]) = v0;
  *(uint4*)(&t[r][c + 8]) = v1;
  __syncthreads();
  u16 tmp[16];
#pragma unroll
  for (int j = 0; j < 16; ++j) tmp[j] = t[c + j][r];
  uint4* dst = (uint4*)(outp + (size_t)(d0 + r) * 2048 + s0 + c);
  dst[0] = *(uint4*)(&tmp[0]);
  dst[1] = *(uint4*)(&tmp[8]);
}

// ---------- lsum v2: K-tile LDS sharing ----------
__global__ __launch_bounds__(512, 2) void lsum_kernel(const u16* __restrict__ Qp,
                                                      const u16* __restrict__ Kp,
                                                      float* __restrict__ invl) {
  __shared__ __align__(16) u16 Ks[2][8192];          // 2 x 16KB, chunk-swizzled
  const int tid = threadIdx.x;
  const int wave = tid >> 6, lane = tid & 63;
  const int g = lane >> 4, l16 = lane & 15;
  const int id = blockIdx.x;
  const int xcd = id & 7;
  const int r = id >> 3;                  // 0..31
  const int bh = xcd * 4 + (r & 3);       // all blocks of bh on one XCD
  const int p = r >> 2;                   // 0..7
  const int strip = wave >> 2;            // 0 = heavy, 1 = light
  const int pw = wave & 3;
  const int nktH = 16 - p, nktL = p + 1;
  const int myNkt = strip ? nktL : nktH;
  const int myBase = (strip ? p : 15 - p) * 128 + pw * 32;
  const int b = bh >> 3, h = bh & 7;
  const char* KhB = (const char*)Kp + (size_t)b * 2097152 + h * 128;  // K row = 1024B
  const u16* Qh = Qp + (size_t)b * 1048576 + h * 64;
  char* KsC = (char*)Ks;

  const int sr_r = tid >> 2;
  const int sr_c = (tid & 3) * 2;
  const size_t sr_src = (size_t)sr_r * 1024 + sr_c * 16;
  const int sr_d0 = sr_r * 128 + ((sr_c ^ (sr_r & 7)) << 4);
  const int sr_d1 = sr_r * 128 + (((sr_c + 1) ^ (sr_r & 7)) << 4);
  uint4 sr[2];

#define STAGE_LOAD(KT)                                                         \
  { sr[0] = *(const uint4*)(KhB + (size_t)(KT) * 131072 + sr_src);             \
    sr[1] = *(const uint4*)(KhB + (size_t)(KT) * 131072 + sr_src + 16); }
#define STAGE_WRITE(CUR)                                                       \
  { *(uint4*)(KsC + (CUR) * 16384 + sr_d0) = sr[0];                            \
    *(uint4*)(KsC + (CUR) * 16384 + sr_d1) = sr[1]; }
#define BAR_READS_DONE()                                                       \
  { asm volatile("" ::: "memory");                                             \
    __builtin_amdgcn_s_barrier();                                              \
    __builtin_amdgcn_sched_barrier(0); }
#define BAR_WRITES_VISIBLE()                                                   \
  { asm volatile("s_waitcnt lgkmcnt(0)" ::: "memory");                         \
    __builtin_amdgcn_sched_barrier(0);                                         \
    __builtin_amdgcn_s_barrier();                                              \
    __builtin_amdgcn_sched_barrier(0); }

  const int qrow0 = myBase + l16;
  const int qrow1 = myBase + 16 + l16;
  bf16x8 q00 = *(const bf16x8*)(Qh + (size_t)qrow0 * 512 + g * 8);
  bf16x8 q01 = *(const bf16x8*)(Qh + (size_t)qrow0 * 512 + 32 + g * 8);
  bf16x8 q10 = *(const bf16x8*)(Qh + (size_t)qrow1 * 512 + g * 8);
  bf16x8 q11 = *(const bf16x8*)(Qh + (size_t)qrow1 * 512 + 32 + g * 8);

  float ls0 = 0.f, ls1 = 0.f;
  STAGE_LOAD(0); STAGE_WRITE(0);
  if (nktH > 1) STAGE_LOAD(1);
  BAR_WRITES_VISIBLE();
  int cur = 0;
  for (int kt = 0; kt < nktH; ++kt) {
    const int ktb = kt * 128;
    const bool act = (kt < myNkt);
    const bool dg = (kt == myNkt - 1);
    const char* Kc = KsC + cur * 16384;
    if (act) {
#pragma unroll
      for (int kf = 0; kf < 8; ++kf) {
        const int ro = (kf * 16 + l16) * 128;
        bf16x8 ka = *(const bf16x8*)(Kc + ro + ((g ^ (l16 & 7)) << 4));
        bf16x8 kb = *(const bf16x8*)(Kc + ro + (((4 + g) ^ (l16 & 7)) << 4));
        const int kbase = ktb + kf * 16 + g * 4;
        f32x4 c0 = {0.f, 0.f, 0.f, 0.f};
        f32x4 c1 = {0.f, 0.f, 0.f, 0.f};
        __builtin_amdgcn_s_setprio(1);
        c0 = MFMA_B16(ka, q00, c0);
        c0 = MFMA_B16(kb, q01, c0);
        c1 = MFMA_B16(ka, q10, c1);
        c1 = MFMA_B16(kb, q11, c1);
        __builtin_amdgcn_s_setprio(0);
        if (dg) {
#pragma unroll
          for (int rr = 0; rr < 4; ++rr) {
            ls0 += (kbase + rr > qrow0) ? 0.f : __expf(c0[rr] * 0.125f);
            ls1 += (kbase + rr > qrow1) ? 0.f : __expf(c1[rr] * 0.125f);
          }
        } else {
          ls0 += __expf(c0[0] * 0.125f) + __expf(c0[1] * 0.125f)
               + __expf(c0[2] * 0.125f) + __expf(c0[3] * 0.125f);
          ls1 += __expf(c1[0] * 0.125f) + __expf(c1[1] * 0.125f)
               + __expf(c1[2] * 0.125f) + __expf(c1[3] * 0.125f);
        }
      }
    }
    if (kt + 1 < nktH) {
      BAR_READS_DONE();
      STAGE_WRITE(cur ^ 1);
      if (kt + 2 < nktH) STAGE_LOAD(kt + 2);
      BAR_WRITES_VISIBLE();
      cur ^= 1;
    }
  }
  ls0 += __shfl_xor(ls0, 16); ls0 += __shfl_xor(ls0, 32);
  ls1 += __shfl_xor(ls1, 16); ls1 += __shfl_xor(ls1, 32);
  if (lane < 16) {
    invl[(size_t)bh * 2048 + qrow0] = 1.f / ls0;
    invl[(size_t)bh * 2048 + qrow1] = 1.f / ls1;
  }
#undef STAGE_LOAD
#undef STAGE_WRITE
#undef BAR_READS_DONE
#undef BAR_WRITES_VISIBLE
}

// ---------- fused causal attention, v14: barrier-free single-wave blocks ----------
// 2048 blocks x 64 thr (1 wave). Wave = (bh XCD-pinned, pair p, unit u):
// processes 16 rows of heavy strip (31-p) for nktH tiles, THEN 16 rows of
// light strip (p) for nktL tiles -> uniform 17 tiles/wave, all waves retire
// together. K/V read directly from global (L2-resident via XCD pin). P in a
// wave-private 4KB LDS buffer (no barriers, in-order DS per wave). nt-stores
// + in-loop zero-fill. Waves drift freely -> store stream desynchronized.
__global__ __launch_bounds__(64) void attn_kernel(const u16* __restrict__ Qp,
                                                  const u16* __restrict__ Kp,
                                                  const u16* __restrict__ Vt,
                                                  const float* __restrict__ invl,
                                                  float* __restrict__ attn_all,
                                                  u16* __restrict__ ctx) {
  __shared__ __align__(16) u16 Plds[2048];           // 4KB, wave-private
  const int lane = threadIdx.x;
  const int g = lane >> 4, l16 = lane & 15;
  const int id = blockIdx.x;
  const int xcd = id & 7;
  int r = id >> 3;                        // 0..255
  const int bh = xcd * 4 + (r & 3);       // all blocks of bh on one XCD
  r >>= 2;                                // 0..63
  const int p = r >> 2;                   // pair 0..15
  const int u = r & 3;                    // unit 0..3
  const int sHi = 31 - p, sLo = p;
  const int nktH = sHi / 2 + 1, nktL = sLo / 2 + 1;
  const int b = bh >> 3, h = bh & 7;
  const u16* Qh = Qp + (size_t)b * 1048576 + h * 64;
  const u16* Kh = Kp + (size_t)b * 1048576 + h * 64;
  const char* VhB = (const char*)Vt + ((size_t)b * 512 + h * 64) * 4096;
  float* attn = attn_all + (size_t)bh * 4194304;
  u16* cbB = ctx + (size_t)b * 1048576 + h * 64;
  char* Pw = (char*)Plds;
  const int swk = (l16 & 7) << 4;
  const f32x4 z4 = {0.f, 0.f, 0.f, 0.f};

#define LGKM0()                                                                \
  { asm volatile("s_waitcnt lgkmcnt(0)" ::: "memory");                         \
    __builtin_amdgcn_sched_barrier(0); }

#pragma unroll 1
  for (int ph = 0; ph < 2; ++ph) {
    const int myS = ph ? sLo : sHi;
    const int nkt = ph ? nktL : nktH;
    const int qr = myS * 64 + u * 16;
    const int qrow = qr + l16;
    bf16x8 q0 = *(const bf16x8*)(Qh + (size_t)qrow * 512 + g * 8);
    bf16x8 q1 = *(const bf16x8*)(Qh + (size_t)qrow * 512 + 32 + g * 8);
    const float inv = invl[(size_t)bh * 2048 + qrow];
    const int z0 = nkt * 128;
    const int vmax = ((16 - nkt + 1) >> 1) * 16;
    const int zstep = (vmax + nkt - 1) / nkt;
    int zv = 0;
    f32x4 oacc[4] = {};
    for (int kt = 0; kt < nkt; ++kt) {
      const int ktb = kt * 128;
      const bool dg = (kt == nkt - 1);
      // QK^T + normalize -> Plds
#pragma unroll
      for (int kf = 0; kf < 8; ++kf) {
        const u16* Krow = Kh + (size_t)(ktb + kf * 16 + l16) * 512;
        bf16x8 k0 = *(const bf16x8*)(Krow + g * 8);
        bf16x8 k1 = *(const bf16x8*)(Krow + 32 + g * 8);
        const int kbase = ktb + kf * 16 + g * 4;
        f32x4 c = {0.f, 0.f, 0.f, 0.f};
        __builtin_amdgcn_s_setprio(1);
        c = MFMA_B16(k0, q0, c);
        c = MFMA_B16(k1, q1, c);
        __builtin_amdgcn_s_setprio(0);
        float pv[4];
#pragma unroll
        for (int rr = 0; rr < 4; ++rr) {
          float e = __expf(c[rr] * 0.125f) * inv;
          pv[rr] = (dg && (kbase + rr > qrow)) ? 0.f : e;
        }
        unsigned lo = (unsigned)f2bf(pv[0]) | ((unsigned)f2bf(pv[1]) << 16);
        unsigned hi = (unsigned)f2bf(pv[2]) | ((unsigned)f2bf(pv[3]) << 16);
        *(uint2*)(Pw + l16 * 256 + ((kf * 32 + g * 8) ^ swk)) = make_uint2(lo, hi);
      }
      LGKM0();
      // PV (V from global/L2)
#pragma unroll
      for (int kb4 = 0; kb4 < 4; ++kb4) {
        bf16x8 pa = *(const bf16x8*)(Pw + l16 * 256 + ((kb4 * 64 + g * 16) ^ swk));
#pragma unroll
        for (int cn = 0; cn < 4; ++cn) {
          bf16x8 vb = *(const bf16x8*)(VhB + (size_t)(cn * 16 + l16) * 4096 +
                                       (ktb + kb4 * 32 + g * 8) * 2);
          __builtin_amdgcn_s_setprio(1);
          oacc[cn] = MFMA_B16(pa, vb, oacc[cn]);
          __builtin_amdgcn_s_setprio(0);
        }
      }
      // attn nt-stores: 2 rows x 512B contiguous per instruction
      {
        const int c32 = lane & 31;
        const int rh = lane >> 5;
#pragma unroll
        for (int i = 0; i < 8; ++i) {
          const int row = i * 2 + rh;
          uint2 pk = *(const uint2*)(Pw + row * 256 + ((c32 * 8) ^ ((row & 7) << 4)));
          f32x4 o;
          o[0] = __uint_as_float(pk.x << 16);
          o[1] = __uint_as_float(pk.x & 0xffff0000u);
          o[2] = __uint_as_float(pk.y << 16);
          o[3] = __uint_as_float(pk.y & 0xffff0000u);
          __builtin_nontemporal_store(o, (f32x4*)(&attn[(size_t)(qr + row) * 2048 + ktb + c32 * 4]));
        }
      }
      // in-loop zero-fill slice (own 16 rows)
      {
        const int zlim = (zstep * (kt + 1) < vmax) ? zstep * (kt + 1) : vmax;
        for (; zv < zlim; ++zv) {
          const int ri = zv & 15;
          const int cs = zv >> 4;
          const int col = z0 + lane * 4 + cs * 256;
          if (col < 2048)
            __builtin_nontemporal_store(
                z4, (f32x4*)(&attn[(size_t)(qr + ri) * 2048 + col]));
        }
      }
    }
    // ctx write
#pragma unroll
    for (int cn = 0; cn < 4; ++cn)
#pragma unroll
      for (int rr = 0; rr < 4; ++rr)
        cbB[(size_t)(qr + g * 4 + rr) * 512 + cn * 16 + l16] = f2bf(oacc[cn][rr]);
  }
#undef LGKM0
}

// ---------- LayerNorm (residual pre-added by gemm_f32out) ----------
__global__ __launch_bounds__(256) void ln_kernel(const float* __restrict__ proj,
                                                 const float* __restrict__ gamma,
                                                 const float* __restrict__ beta,
                                                 float* __restrict__ out) {
  const int wave = threadIdx.x >> 6, lane = threadIdx.x & 63;
  const int row = blockIdx.x * 4 + wave;
  const float4* p4 = (const float4*)(proj + (size_t)row * 512);
  float4 a0 = p4[lane * 2], a1 = p4[lane * 2 + 1];
  float x[8];
  x[0] = a0.x; x[1] = a0.y; x[2] = a0.z; x[3] = a0.w;
  x[4] = a1.x; x[5] = a1.y; x[6] = a1.z; x[7] = a1.w;
  float s = 0.f;
#pragma unroll
  for (int j = 0; j < 8; ++j) s += x[j];
#pragma unroll
  for (int d = 1; d < 64; d <<= 1) s += __shfl_xor(s, d);
  float mu = s * (1.f / 512.f);
  float v = 0.f;
#pragma unroll
  for (int j = 0; j < 8; ++j) { float t = x[j] - mu; v += t * t; }
#pragma unroll
  for (int d = 1; d < 64; d <<= 1) v += __shfl_xor(v, d);
  float rs = rsqrtf(v * (1.f / 512.f) + 1e-5f);
  const float4* g4 = (const float4*)gamma;
  const float4* b4 = (const float4*)beta;
  float4 g0 = g4[lane * 2], g1 = g4[lane * 2 + 1];
  float4 bb0 = b4[lane * 2], bb1 = b4[lane * 2 + 1];
  float4 y0, y1;
  y0.x = (x[0] - mu) * rs * g0.x + bb0.x;
  y0.y = (x[1] - mu) * rs * g0.y + bb0.y;
  y0.z = (x[2] - mu) * rs * g0.z + bb0.z;
  y0.w = (x[3] - mu) * rs * g0.w + bb0.w;
  y1.x = (x[4] - mu) * rs * g1.x + bb1.x;
  y1.y = (x[5] - mu) * rs * g1.y + bb1.y;
  y1.z = (x[6] - mu) * rs * g1.z + bb1.z;
  y1.w = (x[7] - mu) * rs * g1.w + bb1.w;
  float4* o4 = (float4*)(out + (size_t)row * 512);
  o4[lane * 2] = y0;
  o4[lane * 2 + 1] = y1;
}

// ---------- launch ----------
extern "C" void kernel_launch(void* const* d_in, const int* in_sizes, int n_in,
                              void* d_out, int out_size, void* d_ws, size_t ws_size,
                              hipStream_t stream) {
  (void)in_sizes; (void)n_in; (void)out_size; (void)ws_size;
  const float* inQ = (const float*)d_in[0];
  const float* inK = (const float*)d_in[1];
  const float* inV = (const float*)d_in[2];
  const float* Wq = (const float*)d_in[4];
  const float* Wk = (const float*)d_in[5];
  const float* Wv = (const float*)d_in[6];
  const float* Wo = (const float*)d_in[7];
  const float* gamma = (const float*)d_in[8];
  const float* beta = (const float*)d_in[9];

  float* out = (float*)d_out;
  float* attn = out + (size_t)4 * 2048 * 512;

  char* ws = (char*)d_ws;
  u16* Qp  = (u16*)(ws + 0);
  u16* Kp  = (u16*)(ws + 8388608);
  u16* Vp  = (u16*)(ws + 16777216);      // freed after transpose_v -> reused for invl
  u16* Vt  = (u16*)(ws + 25165824);
  u16* ctx = (u16*)(ws + 33554432);
  u16* Wbf = (u16*)(ws + 41943040);
  float* invl = (float*)(ws + 16777216); // 256 KB, overlaps dead Vp
  float* proj = (float*)(ws + 0);        // reuses Qp+Kp after attention
  u16* Xbf = (u16*)attn;

  cvt3<<<2048, 256, 0, stream>>>(inQ, inK, inV, Xbf, 1048576, 4194304);
  cvtW<<<256, 256, 0, stream>>>(Wq, Wk, Wv, Wo, Wbf, 65536, 262144);
  gemm_qkv<<<dim3(64, 4, 3), 256, 0, stream>>>(Xbf, Wbf, Qp);
  transpose_v<<<dim3(32, 8, 4), 256, 0, stream>>>(Vp, Vt);
  lsum_kernel<<<256, 512, 0, stream>>>(Qp, Kp, invl);
  attn_kernel<<<dim3(2048), 64, 0, stream>>>(Qp, Kp, Vt, invl, attn, ctx);
  gemm_f32out<<<dim3(64, 4, 1), 256, 0, stream>>>(ctx, Wbf + (size_t)3 * 262144, proj, inQ);
  ln_kernel<<<2048, 256, 0, stream>>>(proj, gamma, beta, out);
}

// Round 18
// 271.297 us; speedup vs baseline: 1.0956x; 1.0956x over previous
//
#include <hip/hip_runtime.h>

typedef unsigned short u16;
typedef __bf16 bf16x8 __attribute__((ext_vector_type(8)));
typedef float f32x4 __attribute__((ext_vector_type(4)));
typedef unsigned short u16x4 __attribute__((ext_vector_type(4)));

#define MFMA_B16(a, b, c) __builtin_amdgcn_mfma_f32_16x16x32_bf16((a), (b), (c), 0, 0, 0)

// ---------- helpers ----------
__device__ __forceinline__ u16 f2bf(float f) {
  unsigned int u = __float_as_uint(f);
  u += 0x7FFFu + ((u >> 16) & 1u);   // RNE
  return (u16)(u >> 16);
}

__device__ __forceinline__ u16x4 f4_to_bf4(float4 v) {
  u16x4 r;
  r[0] = f2bf(v.x); r[1] = f2bf(v.y); r[2] = f2bf(v.z); r[3] = f2bf(v.w);
  return r;
}

// async 16B/lane global->LDS (dest = wave-uniform base + lane*16)
__device__ __forceinline__ void gl_lds16(const u16* g, u16* l) {
  __builtin_amdgcn_global_load_lds(
      (const __attribute__((address_space(1))) void*)g,
      (__attribute__((address_space(3))) void*)l, 16, 0, 0);
}

// ---------- f32 -> bf16 converts ----------
__global__ __launch_bounds__(256) void cvt3(const float* __restrict__ a,
                                            const float* __restrict__ b,
                                            const float* __restrict__ c,
                                            u16* __restrict__ dst, int n4, int n) {
  int i = blockIdx.x * 256 + threadIdx.x;
  int stride = gridDim.x * 256;
  const float4* a4 = (const float4*)a;
  const float4* b4 = (const float4*)b;
  const float4* c4 = (const float4*)c;
  u16x4* d0 = (u16x4*)dst;
  u16x4* d1 = (u16x4*)(dst + (size_t)n);
  u16x4* d2 = (u16x4*)(dst + (size_t)2 * n);
  for (; i < n4; i += stride) {
    d0[i] = f4_to_bf4(a4[i]);
    d1[i] = f4_to_bf4(b4[i]);
    d2[i] = f4_to_bf4(c4[i]);
  }
}

__global__ __launch_bounds__(256) void cvtW(const float* __restrict__ a,
                                            const float* __restrict__ b,
                                            const float* __restrict__ c,
                                            const float* __restrict__ d,
                                            u16* __restrict__ dst, int n4, int n) {
  int i = blockIdx.x * 256 + threadIdx.x;
  int stride = gridDim.x * 256;
  const float4* a4 = (const float4*)a;
  const float4* b4 = (const float4*)b;
  const float4* c4 = (const float4*)c;
  const float4* d4 = (const float4*)d;
  u16x4* o0 = (u16x4*)dst;
  u16x4* o1 = (u16x4*)(dst + (size_t)n);
  u16x4* o2 = (u16x4*)(dst + (size_t)2 * n);
  u16x4* o3 = (u16x4*)(dst + (size_t)3 * n);
  for (; i < n4; i += stride) {
    o0[i] = f4_to_bf4(a4[i]);
    o1[i] = f4_to_bf4(b4[i]);
    o2[i] = f4_to_bf4(c4[i]);
    o3[i] = f4_to_bf4(d4[i]);
  }
}

// ---------- B-transposed bf16 GEMM v2: global_load_lds staging ----------
template <bool OUT_F32>
__device__ __forceinline__ void gemm_body(const u16* __restrict__ A,
                                          const u16* __restrict__ Bw,
                                          u16* __restrict__ Cb, float* __restrict__ Cf,
                                          const float* __restrict__ resid,
                                          int bm, int bn) {
  __shared__ __align__(16) u16 As[128 * 32];
  __shared__ __align__(16) u16 Bs[128 * 32];
  const int tid = threadIdx.x;
  const int wave = tid >> 6, lane = tid & 63;
  const int g = lane >> 4, l16 = lane & 15;
  const int wr = (wave >> 1) * 64, wc = (wave & 1) * 64;

  const int r0 = wave * 32 + (lane >> 2);
  const int r1 = r0 + 16;
  const int c0 = (((lane & 3) ^ ((r0 >> 1) & 3)) << 3);
  const int c1 = (((lane & 3) ^ ((r1 >> 1) & 3)) << 3);
  const u16* Ar0 = A + (size_t)(bm + r0) * 512 + c0;
  const u16* Ar1 = A + (size_t)(bm + r1) * 512 + c1;
  const u16* Br0 = Bw + (size_t)(bn + r0) * 512 + c0;
  const u16* Br1 = Bw + (size_t)(bn + r1) * 512 + c1;
  u16* Ad0 = As + (wave * 32) * 32;
  u16* Ad1 = As + (wave * 32 + 16) * 32;
  u16* Bd0 = Bs + (wave * 32) * 32;
  u16* Bd1 = Bs + (wave * 32 + 16) * 32;

  f32x4 acc[4][4] = {};
  for (int k0 = 0; k0 < 512; k0 += 32) {
    gl_lds16(Ar0 + k0, Ad0);
    gl_lds16(Ar1 + k0, Ad1);
    gl_lds16(Br0 + k0, Bd0);
    gl_lds16(Br1 + k0, Bd1);
    __syncthreads();
    bf16x8 af[4], bfr[4];
#pragma unroll
    for (int i = 0; i < 4; ++i) {
      const int ar = wr + i * 16 + l16;
      af[i] = *(const bf16x8*)((const char*)As + ar * 64 + ((g ^ ((ar >> 1) & 3)) << 4));
    }
#pragma unroll
    for (int j = 0; j < 4; ++j) {
      const int br = wc + j * 16 + l16;
      bfr[j] = *(const bf16x8*)((const char*)Bs + br * 64 + ((g ^ ((br >> 1) & 3)) << 4));
    }
#pragma unroll
    for (int i = 0; i < 4; ++i)
#pragma unroll
      for (int j = 0; j < 4; ++j)
        acc[i][j] = MFMA_B16(af[i], bfr[j], acc[i][j]);
    __syncthreads();
  }
#pragma unroll
  for (int i = 0; i < 4; ++i)
#pragma unroll
    for (int j = 0; j < 4; ++j)
#pragma unroll
      for (int r = 0; r < 4; ++r) {
        int row = bm + wr + i * 16 + g * 4 + r;
        int col = bn + wc + j * 16 + l16;
        if constexpr (OUT_F32)
          Cf[(size_t)row * 512 + col] = acc[i][j][r] + resid[(size_t)row * 512 + col];
        else
          Cb[(size_t)row * 512 + col] = f2bf(acc[i][j][r]);
      }
}

__global__ __launch_bounds__(256) void gemm_qkv(const u16* __restrict__ Xbf,
                                                const u16* __restrict__ Wbf,
                                                u16* __restrict__ QKVp) {
  int z = blockIdx.z;
  gemm_body<false>(Xbf + (size_t)z * 4194304, Wbf + (size_t)z * 262144,
                   QKVp + (size_t)z * 4194304, nullptr, nullptr,
                   blockIdx.x * 128, blockIdx.y * 128);
}

__global__ __launch_bounds__(256) void gemm_f32out(const u16* __restrict__ A,
                                                   const u16* __restrict__ Bw,
                                                   float* __restrict__ C,
                                                   const float* __restrict__ resid) {
  gemm_body<true>(A, Bw, nullptr, C, resid, blockIdx.x * 128, blockIdx.y * 128);
}

// ---------- V transpose: Vp[b][s][d] (bf16) -> Vt[b][d][s] (bf16) ----------
__global__ __launch_bounds__(256) void transpose_v(const u16* __restrict__ Vp,
                                                   u16* __restrict__ Vt) {
  __shared__ __align__(16) u16 t[64][72];
  const int b = blockIdx.z;
  const int s0 = blockIdx.x * 64, d0 = blockIdx.y * 64;
  const u16* in = Vp + (size_t)b * 2048 * 512;
  u16* outp = Vt + (size_t)b * 512 * 2048;
  const int tid = threadIdx.x;
  const int r = tid >> 2;
  const int c = (tid & 3) * 16;
  const uint4* src = (const uint4*)(in + (size_t)(s0 + r) * 512 + d0 + c);
  uint4 v0 = src[0], v1 = src[1];
  *(uint4*)(&t[r][c]) = v0;
  *(uint4*)(&t[r][c + 8]) = v1;
  __syncthreads();
  u16 tmp[16];
#pragma unroll
  for (int j = 0; j < 16; ++j) tmp[j] = t[c + j][r];
  uint4* dst = (uint4*)(outp + (size_t)(d0 + r) * 2048 + s0 + c);
  dst[0] = *(uint4*)(&tmp[0]);
  dst[1] = *(uint4*)(&tmp[8]);
}

// ---------- lsum v2: K-tile LDS sharing ----------
__global__ __launch_bounds__(512, 2) void lsum_kernel(const u16* __restrict__ Qp,
                                                      const u16* __restrict__ Kp,
                                                      float* __restrict__ invl) {
  __shared__ __align__(16) u16 Ks[2][8192];          // 2 x 16KB, chunk-swizzled
  const int tid = threadIdx.x;
  const int wave = tid >> 6, lane = tid & 63;
  const int g = lane >> 4, l16 = lane & 15;
  const int id = blockIdx.x;
  const int xcd = id & 7;
  const int r = id >> 3;                  // 0..31
  const int bh = xcd * 4 + (r & 3);       // all blocks of bh on one XCD
  const int p = r >> 2;                   // 0..7
  const int strip = wave >> 2;            // 0 = heavy, 1 = light
  const int pw = wave & 3;
  const int nktH = 16 - p, nktL = p + 1;
  const int myNkt = strip ? nktL : nktH;
  const int myBase = (strip ? p : 15 - p) * 128 + pw * 32;
  const int b = bh >> 3, h = bh & 7;
  const char* KhB = (const char*)Kp + (size_t)b * 2097152 + h * 128;  // K row = 1024B
  const u16* Qh = Qp + (size_t)b * 1048576 + h * 64;
  char* KsC = (char*)Ks;

  const int sr_r = tid >> 2;
  const int sr_c = (tid & 3) * 2;
  const size_t sr_src = (size_t)sr_r * 1024 + sr_c * 16;
  const int sr_d0 = sr_r * 128 + ((sr_c ^ (sr_r & 7)) << 4);
  const int sr_d1 = sr_r * 128 + (((sr_c + 1) ^ (sr_r & 7)) << 4);
  uint4 sr[2];

#define STAGE_LOAD(KT)                                                         \
  { sr[0] = *(const uint4*)(KhB + (size_t)(KT) * 131072 + sr_src);             \
    sr[1] = *(const uint4*)(KhB + (size_t)(KT) * 131072 + sr_src + 16); }
#define STAGE_WRITE(CUR)                                                       \
  { *(uint4*)(KsC + (CUR) * 16384 + sr_d0) = sr[0];                            \
    *(uint4*)(KsC + (CUR) * 16384 + sr_d1) = sr[1]; }
#define BAR_READS_DONE()                                                       \
  { asm volatile("" ::: "memory");                                             \
    __builtin_amdgcn_s_barrier();                                              \
    __builtin_amdgcn_sched_barrier(0); }
#define BAR_WRITES_VISIBLE()                                                   \
  { asm volatile("s_waitcnt lgkmcnt(0)" ::: "memory");                         \
    __builtin_amdgcn_sched_barrier(0);                                         \
    __builtin_amdgcn_s_barrier();                                              \
    __builtin_amdgcn_sched_barrier(0); }

  const int qrow0 = myBase + l16;
  const int qrow1 = myBase + 16 + l16;
  bf16x8 q00 = *(const bf16x8*)(Qh + (size_t)qrow0 * 512 + g * 8);
  bf16x8 q01 = *(const bf16x8*)(Qh + (size_t)qrow0 * 512 + 32 + g * 8);
  bf16x8 q10 = *(const bf16x8*)(Qh + (size_t)qrow1 * 512 + g * 8);
  bf16x8 q11 = *(const bf16x8*)(Qh + (size_t)qrow1 * 512 + 32 + g * 8);

  float ls0 = 0.f, ls1 = 0.f;
  STAGE_LOAD(0); STAGE_WRITE(0);
  if (nktH > 1) STAGE_LOAD(1);
  BAR_WRITES_VISIBLE();
  int cur = 0;
  for (int kt = 0; kt < nktH; ++kt) {
    const int ktb = kt * 128;
    const bool act = (kt < myNkt);
    const bool dg = (kt == myNkt - 1);
    const char* Kc = KsC + cur * 16384;
    if (act) {
#pragma unroll
      for (int kf = 0; kf < 8; ++kf) {
        const int ro = (kf * 16 + l16) * 128;
        bf16x8 ka = *(const bf16x8*)(Kc + ro + ((g ^ (l16 & 7)) << 4));
        bf16x8 kb = *(const bf16x8*)(Kc + ro + (((4 + g) ^ (l16 & 7)) << 4));
        const int kbase = ktb + kf * 16 + g * 4;
        f32x4 c0 = {0.f, 0.f, 0.f, 0.f};
        f32x4 c1 = {0.f, 0.f, 0.f, 0.f};
        __builtin_amdgcn_s_setprio(1);
        c0 = MFMA_B16(ka, q00, c0);
        c0 = MFMA_B16(kb, q01, c0);
        c1 = MFMA_B16(ka, q10, c1);
        c1 = MFMA_B16(kb, q11, c1);
        __builtin_amdgcn_s_setprio(0);
        if (dg) {
#pragma unroll
          for (int rr = 0; rr < 4; ++rr) {
            ls0 += (kbase + rr > qrow0) ? 0.f : __expf(c0[rr] * 0.125f);
            ls1 += (kbase + rr > qrow1) ? 0.f : __expf(c1[rr] * 0.125f);
          }
        } else {
          ls0 += __expf(c0[0] * 0.125f) + __expf(c0[1] * 0.125f)
               + __expf(c0[2] * 0.125f) + __expf(c0[3] * 0.125f);
          ls1 += __expf(c1[0] * 0.125f) + __expf(c1[1] * 0.125f)
               + __expf(c1[2] * 0.125f) + __expf(c1[3] * 0.125f);
        }
      }
    }
    if (kt + 1 < nktH) {
      BAR_READS_DONE();
      STAGE_WRITE(cur ^ 1);
      if (kt + 2 < nktH) STAGE_LOAD(kt + 2);
      BAR_WRITES_VISIBLE();
      cur ^= 1;
    }
  }
  ls0 += __shfl_xor(ls0, 16); ls0 += __shfl_xor(ls0, 32);
  ls1 += __shfl_xor(ls1, 16); ls1 += __shfl_xor(ls1, 32);
  if (lane < 16) {
    invl[(size_t)bh * 2048 + qrow0] = 1.f / ls0;
    invl[(size_t)bh * 2048 + qrow1] = 1.f / ls1;
  }
#undef STAGE_LOAD
#undef STAGE_WRITE
#undef BAR_READS_DONE
#undef BAR_WRITES_VISIBLE
}

// ---------- fused causal attention, v15: V staged in LDS + PLAIN stores ----------
// R16 structure (512 blocks x 8 waves, strip split H/L, K dbuf, in-loop zf),
// with: (1) V tile ALSO double-buffered in LDS (staged once per block, not
// 8x per-wave from L2); (2) plain stores for attn + zf (L2 write-combining
// path, safe now that no hot read depends on L2 residency). LDS 96KB ->
// 1 block/CU (8 waves).
__global__ __launch_bounds__(512, 2) void attn_kernel(const u16* __restrict__ Qp,
                                                      const u16* __restrict__ Kp,
                                                      const u16* __restrict__ Vt,
                                                      const float* __restrict__ invl,
                                                      float* __restrict__ attn_all,
                                                      u16* __restrict__ ctx) {
  __shared__ __align__(16) u16 Ks[2][8192];          // 2 x 16KB K tiles
  __shared__ __align__(16) u16 Vs[2][8192];          // 2 x 16KB V tiles
  __shared__ __align__(16) u16 Plds[8][16][128];     // 32KB
  const int tid = threadIdx.x;
  const int wave = tid >> 6, lane = tid & 63;
  const int g = lane >> 4, l16 = lane & 15;
  const int strip = wave >> 2;             // 0 = heavy, 1 = light
  const int pw = wave & 3;
  const int id = blockIdx.x;
  const int r8 = id >> 3;
  const int bh = (id & 7) * 4 + (r8 & 3);
  const int pair = r8 >> 2;
  const int sLo = pair, sHi = 31 - pair;
  const int b = bh >> 3, h = bh & 7;
  const int nktH = sHi / 2 + 1, nktL = sLo / 2 + 1;
  const int myNkt = strip ? nktL : nktH;
  const int myS = strip ? sLo : sHi;
  const char* KhB = (const char*)Kp + (size_t)b * 2097152 + h * 128;
  const char* VhB = (const char*)Vt + ((size_t)b * 512 + h * 64) * 4096;
  const u16* Qh = Qp + (size_t)b * 1048576 + h * 64;
  float* attn = attn_all + (size_t)bh * 4194304;
  char* KsC = (char*)Ks;
  char* VsC = (char*)Vs;
  char* Pw = (char*)&Plds[wave][0][0];
  const int swk = (l16 & 7) << 4;

  // K staging: thread t -> K row t>>2 (0..127), chunks (t&3)*2, (t&3)*2+1
  const int kr = tid >> 2;
  const int kc = (tid & 3) * 2;
  const size_t k_src = (size_t)kr * 1024 + kc * 16;
  const int k_d0 = kr * 128 + ((kc ^ (kr & 7)) << 4);
  const int k_d1 = kr * 128 + (((kc + 1) ^ (kr & 7)) << 4);
  // V staging: thread t -> V row t>>3 (0..63), chunks (t&7)*2, (t&7)*2+1
  const int vr = tid >> 3;
  const int vc = (tid & 7) * 2;
  const size_t v_src = (size_t)vr * 4096 + vc * 16;
  const int v_d0 = vr * 256 + ((vc ^ (vr & 7)) << 4);
  const int v_d1 = vr * 256 + (((vc + 1) ^ (vr & 7)) << 4);
  uint4 sk[2], sv[2];

#define STAGE_LOAD(KT)                                                         \
  { sk[0] = *(const uint4*)(KhB + (size_t)(KT) * 131072 + k_src);              \
    sk[1] = *(const uint4*)(KhB + (size_t)(KT) * 131072 + k_src + 16);         \
    sv[0] = *(const uint4*)(VhB + (size_t)(KT) * 256 + v_src);                 \
    sv[1] = *(const uint4*)(VhB + (size_t)(KT) * 256 + v_src + 16); }
#define STAGE_WRITE(CUR)                                                       \
  { *(uint4*)(KsC + (CUR) * 16384 + k_d0) = sk[0];                             \
    *(uint4*)(KsC + (CUR) * 16384 + k_d1) = sk[1];                             \
    *(uint4*)(VsC + (CUR) * 16384 + v_d0) = sv[0];                             \
    *(uint4*)(VsC + (CUR) * 16384 + v_d1) = sv[1]; }
#define BAR_READS_DONE()                                                       \
  { asm volatile("" ::: "memory");                                             \
    __builtin_amdgcn_s_barrier();                                              \
    __builtin_amdgcn_sched_barrier(0); }
#define BAR_WRITES_VISIBLE()                                                   \
  { asm volatile("s_waitcnt lgkmcnt(0)" ::: "memory");                         \
    __builtin_amdgcn_sched_barrier(0);                                         \
    __builtin_amdgcn_s_barrier();                                              \
    __builtin_amdgcn_sched_barrier(0); }

  const int qr = myS * 64 + pw * 16;
  const int qrow = qr + l16;

  bf16x8 q0 = *(const bf16x8*)(Qh + (size_t)qrow * 512 + g * 8);
  bf16x8 q1 = *(const bf16x8*)(Qh + (size_t)qrow * 512 + 32 + g * 8);
  const float inv = invl[(size_t)bh * 2048 + qrow];

  // in-loop zero-fill state
  const int z0 = myNkt * 128;
  const int vmax = ((16 - myNkt + 1) >> 1) * 16;
  const int zstep = (vmax + nktH - 1) / nktH;
  int zv = 0;
  const f32x4 z4 = {0.f, 0.f, 0.f, 0.f};

  f32x4 oacc[4] = {};
  {
    STAGE_LOAD(0); STAGE_WRITE(0);
    if (nktH > 1) STAGE_LOAD(1);
    BAR_WRITES_VISIBLE();
    int cur = 0;
    for (int kt = 0; kt < nktH; ++kt) {
      const int ktb = kt * 128;
      const bool act = (kt < myNkt);
      const bool dg = (kt == myNkt - 1);
      const char* Kc = KsC + cur * 16384;
      const char* Vc = VsC + cur * 16384;
      if (act) {
#pragma unroll
        for (int kf = 0; kf < 8; ++kf) {
          const int ro = (kf * 16 + l16) * 128;
          bf16x8 ka = *(const bf16x8*)(Kc + ro + ((g ^ (l16 & 7)) << 4));
          bf16x8 kb = *(const bf16x8*)(Kc + ro + (((4 + g) ^ (l16 & 7)) << 4));
          const int kbase = ktb + kf * 16 + g * 4;
          f32x4 c = {0.f, 0.f, 0.f, 0.f};
          __builtin_amdgcn_s_setprio(1);
          c = MFMA_B16(ka, q0, c);
          c = MFMA_B16(kb, q1, c);
          __builtin_amdgcn_s_setprio(0);
          float p[4];
#pragma unroll
          for (int r = 0; r < 4; ++r) {
            float e = __expf(c[r] * 0.125f) * inv;
            p[r] = (dg && (kbase + r > qrow)) ? 0.f : e;
          }
          unsigned lo = (unsigned)f2bf(p[0]) | ((unsigned)f2bf(p[1]) << 16);
          unsigned hi = (unsigned)f2bf(p[2]) | ((unsigned)f2bf(p[3]) << 16);
          *(uint2*)(Pw + l16 * 256 + ((kf * 32 + g * 8) ^ swk)) = make_uint2(lo, hi);
        }
        // PV from LDS V (row-XOR swizzled; 2-way = free)
#pragma unroll
        for (int kb4 = 0; kb4 < 4; ++kb4) {
          bf16x8 pa = *(const bf16x8*)(Pw + l16 * 256 + ((kb4 * 64 + g * 16) ^ swk));
#pragma unroll
          for (int cn = 0; cn < 4; ++cn) {
            const int vrow = cn * 16 + l16;
            bf16x8 vb = *(const bf16x8*)(Vc + vrow * 256 +
                                         (((kb4 * 4 + g) ^ (vrow & 7)) << 4));
            __builtin_amdgcn_s_setprio(1);
            oacc[cn] = MFMA_B16(pa, vb, oacc[cn]);
            __builtin_amdgcn_s_setprio(0);
          }
        }
        // attn plain stores: 2 rows x 512B contiguous per instruction
        {
          const int c32 = lane & 31;
          const int rh = lane >> 5;
#pragma unroll
          for (int i = 0; i < 8; ++i) {
            const int row = i * 2 + rh;
            uint2 pk = *(const uint2*)(Pw + row * 256 + ((c32 * 8) ^ ((row & 7) << 4)));
            f32x4 o;
            o[0] = __uint_as_float(pk.x << 16);
            o[1] = __uint_as_float(pk.x & 0xffff0000u);
            o[2] = __uint_as_float(pk.y << 16);
            o[3] = __uint_as_float(pk.y & 0xffff0000u);
            *(f32x4*)(&attn[(size_t)(qr + row) * 2048 + ktb + c32 * 4]) = o;
          }
        }
      }
      // in-loop zero-fill slice (plain stores)
      {
        const int zlim = (zstep * (kt + 1) < vmax) ? zstep * (kt + 1) : vmax;
        for (; zv < zlim; ++zv) {
          const int ri = zv & 15;
          const int cs = zv >> 4;
          const int col = z0 + lane * 4 + cs * 256;
          if (col < 2048)
            *(f32x4*)(&attn[(size_t)(myS * 64 + pw + ri * 4) * 2048 + col]) = z4;
        }
      }
      if (kt + 1 < nktH) {
        BAR_READS_DONE();
        STAGE_WRITE(cur ^ 1);
        if (kt + 2 < nktH) STAGE_LOAD(kt + 2);
        BAR_WRITES_VISIBLE();
        cur ^= 1;
      }
    }
  }

  // ctx write
  u16* cb = ctx + (size_t)b * 1048576 + h * 64;
#pragma unroll
  for (int cn = 0; cn < 4; ++cn)
#pragma unroll
    for (int r = 0; r < 4; ++r)
      cb[(size_t)(qr + g * 4 + r) * 512 + cn * 16 + l16] = f2bf(oacc[cn][r]);
#undef STAGE_LOAD
#undef STAGE_WRITE
#undef BAR_READS_DONE
#undef BAR_WRITES_VISIBLE
}

// ---------- LayerNorm (residual pre-added by gemm_f32out) ----------
__global__ __launch_bounds__(256) void ln_kernel(const float* __restrict__ proj,
                                                 const float* __restrict__ gamma,
                                                 const float* __restrict__ beta,
                                                 float* __restrict__ out) {
  const int wave = threadIdx.x >> 6, lane = threadIdx.x & 63;
  const int row = blockIdx.x * 4 + wave;
  const float4* p4 = (const float4*)(proj + (size_t)row * 512);
  float4 a0 = p4[lane * 2], a1 = p4[lane * 2 + 1];
  float x[8];
  x[0] = a0.x; x[1] = a0.y; x[2] = a0.z; x[3] = a0.w;
  x[4] = a1.x; x[5] = a1.y; x[6] = a1.z; x[7] = a1.w;
  float s = 0.f;
#pragma unroll
  for (int j = 0; j < 8; ++j) s += x[j];
#pragma unroll
  for (int d = 1; d < 64; d <<= 1) s += __shfl_xor(s, d);
  float mu = s * (1.f / 512.f);
  float v = 0.f;
#pragma unroll
  for (int j = 0; j < 8; ++j) { float t = x[j] - mu; v += t * t; }
#pragma unroll
  for (int d = 1; d < 64; d <<= 1) v += __shfl_xor(v, d);
  float rs = rsqrtf(v * (1.f / 512.f) + 1e-5f);
  const float4* g4 = (const float4*)gamma;
  const float4* b4 = (const float4*)beta;
  float4 g0 = g4[lane * 2], g1 = g4[lane * 2 + 1];
  float4 bb0 = b4[lane * 2], bb1 = b4[lane * 2 + 1];
  float4 y0, y1;
  y0.x = (x[0] - mu) * rs * g0.x + bb0.x;
  y0.y = (x[1] - mu) * rs * g0.y + bb0.y;
  y0.z = (x[2] - mu) * rs * g0.z + bb0.z;
  y0.w = (x[3] - mu) * rs * g0.w + bb0.w;
  y1.x = (x[4] - mu) * rs * g1.x + bb1.x;
  y1.y = (x[5] - mu) * rs * g1.y + bb1.y;
  y1.z = (x[6] - mu) * rs * g1.z + bb1.z;
  y1.w = (x[7] - mu) * rs * g1.w + bb1.w;
  float4* o4 = (float4*)(out + (size_t)row * 512);
  o4[lane * 2] = y0;
  o4[lane * 2 + 1] = y1;
}

// ---------- launch ----------
extern "C" void kernel_launch(void* const* d_in, const int* in_sizes, int n_in,
                              void* d_out, int out_size, void* d_ws, size_t ws_size,
                              hipStream_t stream) {
  (void)in_sizes; (void)n_in; (void)out_size; (void)ws_size;
  const float* inQ = (const float*)d_in[0];
  const float* inK = (const float*)d_in[1];
  const float* inV = (const float*)d_in[2];
  const float* Wq = (const float*)d_in[4];
  const float* Wk = (const float*)d_in[5];
  const float* Wv = (const float*)d_in[6];
  const float* Wo = (const float*)d_in[7];
  const float* gamma = (const float*)d_in[8];
  const float* beta = (const float*)d_in[9];

  float* out = (float*)d_out;
  float* attn = out + (size_t)4 * 2048 * 512;

  char* ws = (char*)d_ws;
  u16* Qp  = (u16*)(ws + 0);
  u16* Kp  = (u16*)(ws + 8388608);
  u16* Vp  = (u16*)(ws + 16777216);      // freed after transpose_v -> reused for invl
  u16* Vt  = (u16*)(ws + 25165824);
  u16* ctx = (u16*)(ws + 33554432);
  u16* Wbf = (u16*)(ws + 41943040);
  float* invl = (float*)(ws + 16777216); // 256 KB, overlaps dead Vp
  float* proj = (float*)(ws + 0);        // reuses Qp+Kp after attention
  u16* Xbf = (u16*)attn;

  cvt3<<<2048, 256, 0, stream>>>(inQ, inK, inV, Xbf, 1048576, 4194304);
  cvtW<<<256, 256, 0, stream>>>(Wq, Wk, Wv, Wo, Wbf, 65536, 262144);
  gemm_qkv<<<dim3(64, 4, 3), 256, 0, stream>>>(Xbf, Wbf, Qp);
  transpose_v<<<dim3(32, 8, 4), 256, 0, stream>>>(Vp, Vt);
  lsum_kernel<<<256, 512, 0, stream>>>(Qp, Kp, invl);
  attn_kernel<<<dim3(512), 512, 0, stream>>>(Qp, Kp, Vt, invl, attn, ctx);
  gemm_f32out<<<dim3(64, 4, 1), 256, 0, stream>>>(ctx, Wbf + (size_t)3 * 262144, proj, inQ);
  ln_kernel<<<2048, 256, 0, stream>>>(proj, gamma, beta, out);
}

// Round 19
// 235.511 us; speedup vs baseline: 1.2621x; 1.1520x over previous
//
#include <hip/hip_runtime.h>

typedef unsigned short u16;
typedef __bf16 bf16x8 __attribute__((ext_vector_type(8)));
typedef float f32x4 __attribute__((ext_vector_type(4)));
typedef unsigned short u16x4 __attribute__((ext_vector_type(4)));

#define MFMA_B16(a, b, c) __builtin_amdgcn_mfma_f32_16x16x32_bf16((a), (b), (c), 0, 0, 0)

// ---------- helpers ----------
__device__ __forceinline__ u16 f2bf(float f) {
  unsigned int u = __float_as_uint(f);
  u += 0x7FFFu + ((u >> 16) & 1u);   // RNE
  return (u16)(u >> 16);
}

__device__ __forceinline__ u16x4 f4_to_bf4(float4 v) {
  u16x4 r;
  r[0] = f2bf(v.x); r[1] = f2bf(v.y); r[2] = f2bf(v.z); r[3] = f2bf(v.w);
  return r;
}

// async 16B/lane global->LDS (dest = wave-uniform base + lane*16)
__device__ __forceinline__ void gl_lds16(const u16* g, u16* l) {
  __builtin_amdgcn_global_load_lds(
      (const __attribute__((address_space(1))) void*)g,
      (__attribute__((address_space(3))) void*)l, 16, 0, 0);
}

// ---------- f32 -> bf16 converts ----------
__global__ __launch_bounds__(256) void cvt3(const float* __restrict__ a,
                                            const float* __restrict__ b,
                                            const float* __restrict__ c,
                                            u16* __restrict__ dst, int n4, int n) {
  int i = blockIdx.x * 256 + threadIdx.x;
  int stride = gridDim.x * 256;
  const float4* a4 = (const float4*)a;
  const float4* b4 = (const float4*)b;
  const float4* c4 = (const float4*)c;
  u16x4* d0 = (u16x4*)dst;
  u16x4* d1 = (u16x4*)(dst + (size_t)n);
  u16x4* d2 = (u16x4*)(dst + (size_t)2 * n);
  for (; i < n4; i += stride) {
    d0[i] = f4_to_bf4(a4[i]);
    d1[i] = f4_to_bf4(b4[i]);
    d2[i] = f4_to_bf4(c4[i]);
  }
}

__global__ __launch_bounds__(256) void cvtW(const float* __restrict__ a,
                                            const float* __restrict__ b,
                                            const float* __restrict__ c,
                                            const float* __restrict__ d,
                                            u16* __restrict__ dst, int n4, int n) {
  int i = blockIdx.x * 256 + threadIdx.x;
  int stride = gridDim.x * 256;
  const float4* a4 = (const float4*)a;
  const float4* b4 = (const float4*)b;
  const float4* c4 = (const float4*)c;
  const float4* d4 = (const float4*)d;
  u16x4* o0 = (u16x4*)dst;
  u16x4* o1 = (u16x4*)(dst + (size_t)n);
  u16x4* o2 = (u16x4*)(dst + (size_t)2 * n);
  u16x4* o3 = (u16x4*)(dst + (size_t)3 * n);
  for (; i < n4; i += stride) {
    o0[i] = f4_to_bf4(a4[i]);
    o1[i] = f4_to_bf4(b4[i]);
    o2[i] = f4_to_bf4(c4[i]);
    o3[i] = f4_to_bf4(d4[i]);
  }
}

// ---------- B-transposed bf16 GEMM v2: global_load_lds staging ----------
template <bool OUT_F32>
__device__ __forceinline__ void gemm_body(const u16* __restrict__ A,
                                          const u16* __restrict__ Bw,
                                          u16* __restrict__ Cb, float* __restrict__ Cf,
                                          const float* __restrict__ resid,
                                          int bm, int bn) {
  __shared__ __align__(16) u16 As[128 * 32];
  __shared__ __align__(16) u16 Bs[128 * 32];
  const int tid = threadIdx.x;
  const int wave = tid >> 6, lane = tid & 63;
  const int g = lane >> 4, l16 = lane & 15;
  const int wr = (wave >> 1) * 64, wc = (wave & 1) * 64;

  const int r0 = wave * 32 + (lane >> 2);
  const int r1 = r0 + 16;
  const int c0 = (((lane & 3) ^ ((r0 >> 1) & 3)) << 3);
  const int c1 = (((lane & 3) ^ ((r1 >> 1) & 3)) << 3);
  const u16* Ar0 = A + (size_t)(bm + r0) * 512 + c0;
  const u16* Ar1 = A + (size_t)(bm + r1) * 512 + c1;
  const u16* Br0 = Bw + (size_t)(bn + r0) * 512 + c0;
  const u16* Br1 = Bw + (size_t)(bn + r1) * 512 + c1;
  u16* Ad0 = As + (wave * 32) * 32;
  u16* Ad1 = As + (wave * 32 + 16) * 32;
  u16* Bd0 = Bs + (wave * 32) * 32;
  u16* Bd1 = Bs + (wave * 32 + 16) * 32;

  f32x4 acc[4][4] = {};
  for (int k0 = 0; k0 < 512; k0 += 32) {
    gl_lds16(Ar0 + k0, Ad0);
    gl_lds16(Ar1 + k0, Ad1);
    gl_lds16(Br0 + k0, Bd0);
    gl_lds16(Br1 + k0, Bd1);
    __syncthreads();
    bf16x8 af[4], bfr[4];
#pragma unroll
    for (int i = 0; i < 4; ++i) {
      const int ar = wr + i * 16 + l16;
      af[i] = *(const bf16x8*)((const char*)As + ar * 64 + ((g ^ ((ar >> 1) & 3)) << 4));
    }
#pragma unroll
    for (int j = 0; j < 4; ++j) {
      const int br = wc + j * 16 + l16;
      bfr[j] = *(const bf16x8*)((const char*)Bs + br * 64 + ((g ^ ((br >> 1) & 3)) << 4));
    }
#pragma unroll
    for (int i = 0; i < 4; ++i)
#pragma unroll
      for (int j = 0; j < 4; ++j)
        acc[i][j] = MFMA_B16(af[i], bfr[j], acc[i][j]);
    __syncthreads();
  }
#pragma unroll
  for (int i = 0; i < 4; ++i)
#pragma unroll
    for (int j = 0; j < 4; ++j)
#pragma unroll
      for (int r = 0; r < 4; ++r) {
        int row = bm + wr + i * 16 + g * 4 + r;
        int col = bn + wc + j * 16 + l16;
        if constexpr (OUT_F32)
          Cf[(size_t)row * 512 + col] = acc[i][j][r] + resid[(size_t)row * 512 + col];
        else
          Cb[(size_t)row * 512 + col] = f2bf(acc[i][j][r]);
      }
}

__global__ __launch_bounds__(256) void gemm_qkv(const u16* __restrict__ Xbf,
                                                const u16* __restrict__ Wbf,
                                                u16* __restrict__ QKVp) {
  int z = blockIdx.z;
  gemm_body<false>(Xbf + (size_t)z * 4194304, Wbf + (size_t)z * 262144,
                   QKVp + (size_t)z * 4194304, nullptr, nullptr,
                   blockIdx.x * 128, blockIdx.y * 128);
}

__global__ __launch_bounds__(256) void gemm_f32out(const u16* __restrict__ A,
                                                   const u16* __restrict__ Bw,
                                                   float* __restrict__ C,
                                                   const float* __restrict__ resid) {
  gemm_body<true>(A, Bw, nullptr, C, resid, blockIdx.x * 128, blockIdx.y * 128);
}

// ---------- V transpose: Vp[b][s][d] (bf16) -> Vt[b][d][s] (bf16) ----------
__global__ __launch_bounds__(256) void transpose_v(const u16* __restrict__ Vp,
                                                   u16* __restrict__ Vt) {
  __shared__ __align__(16) u16 t[64][72];
  const int b = blockIdx.z;
  const int s0 = blockIdx.x * 64, d0 = blockIdx.y * 64;
  const u16* in = Vp + (size_t)b * 2048 * 512;
  u16* outp = Vt + (size_t)b * 512 * 2048;
  const int tid = threadIdx.x;
  const int r = tid >> 2;
  const int c = (tid & 3) * 16;
  const uint4* src = (const uint4*)(in + (size_t)(s0 + r) * 512 + d0 + c);
  uint4 v0 = src[0], v1 = src[1];
  *(uint4*)(&t[r][c]) = v0;
  *(uint4*)(&t[r][c + 8]) = v1;
  __syncthreads();
  u16 tmp[16];
#pragma unroll
  for (int j = 0; j < 16; ++j) tmp[j] = t[c + j][r];
  uint4* dst = (uint4*)(outp + (size_t)(d0 + r) * 2048 + s0 + c);
  dst[0] = *(uint4*)(&tmp[0]);
  dst[1] = *(uint4*)(&tmp[8]);
}

// ---------- lsum v2: K-tile LDS sharing ----------
__global__ __launch_bounds__(512, 2) void lsum_kernel(const u16* __restrict__ Qp,
                                                      const u16* __restrict__ Kp,
                                                      float* __restrict__ invl) {
  __shared__ __align__(16) u16 Ks[2][8192];          // 2 x 16KB, chunk-swizzled
  const int tid = threadIdx.x;
  const int wave = tid >> 6, lane = tid & 63;
  const int g = lane >> 4, l16 = lane & 15;
  const int id = blockIdx.x;
  const int xcd = id & 7;
  const int r = id >> 3;                  // 0..31
  const int bh = xcd * 4 + (r & 3);       // all blocks of bh on one XCD
  const int p = r >> 2;                   // 0..7
  const int strip = wave >> 2;            // 0 = heavy, 1 = light
  const int pw = wave & 3;
  const int nktH = 16 - p, nktL = p + 1;
  const int myNkt = strip ? nktL : nktH;
  const int myBase = (strip ? p : 15 - p) * 128 + pw * 32;
  const int b = bh >> 3, h = bh & 7;
  const char* KhB = (const char*)Kp + (size_t)b * 2097152 + h * 128;  // K row = 1024B
  const u16* Qh = Qp + (size_t)b * 1048576 + h * 64;
  char* KsC = (char*)Ks;

  const int sr_r = tid >> 2;
  const int sr_c = (tid & 3) * 2;
  const size_t sr_src = (size_t)sr_r * 1024 + sr_c * 16;
  const int sr_d0 = sr_r * 128 + ((sr_c ^ (sr_r & 7)) << 4);
  const int sr_d1 = sr_r * 128 + (((sr_c + 1) ^ (sr_r & 7)) << 4);
  uint4 sr[2];

#define STAGE_LOAD(KT)                                                         \
  { sr[0] = *(const uint4*)(KhB + (size_t)(KT) * 131072 + sr_src);             \
    sr[1] = *(const uint4*)(KhB + (size_t)(KT) * 131072 + sr_src + 16); }
#define STAGE_WRITE(CUR)                                                       \
  { *(uint4*)(KsC + (CUR) * 16384 + sr_d0) = sr[0];                            \
    *(uint4*)(KsC + (CUR) * 16384 + sr_d1) = sr[1]; }
#define BAR_READS_DONE()                                                       \
  { asm volatile("" ::: "memory");                                             \
    __builtin_amdgcn_s_barrier();                                              \
    __builtin_amdgcn_sched_barrier(0); }
#define BAR_WRITES_VISIBLE()                                                   \
  { asm volatile("s_waitcnt lgkmcnt(0)" ::: "memory");                         \
    __builtin_amdgcn_sched_barrier(0);                                         \
    __builtin_amdgcn_s_barrier();                                              \
    __builtin_amdgcn_sched_barrier(0); }

  const int qrow0 = myBase + l16;
  const int qrow1 = myBase + 16 + l16;
  bf16x8 q00 = *(const bf16x8*)(Qh + (size_t)qrow0 * 512 + g * 8);
  bf16x8 q01 = *(const bf16x8*)(Qh + (size_t)qrow0 * 512 + 32 + g * 8);
  bf16x8 q10 = *(const bf16x8*)(Qh + (size_t)qrow1 * 512 + g * 8);
  bf16x8 q11 = *(const bf16x8*)(Qh + (size_t)qrow1 * 512 + 32 + g * 8);

  float ls0 = 0.f, ls1 = 0.f;
  STAGE_LOAD(0); STAGE_WRITE(0);
  if (nktH > 1) STAGE_LOAD(1);
  BAR_WRITES_VISIBLE();
  int cur = 0;
  for (int kt = 0; kt < nktH; ++kt) {
    const int ktb = kt * 128;
    const bool act = (kt < myNkt);
    const bool dg = (kt == myNkt - 1);
    const char* Kc = KsC + cur * 16384;
    if (act) {
#pragma unroll
      for (int kf = 0; kf < 8; ++kf) {
        const int ro = (kf * 16 + l16) * 128;
        bf16x8 ka = *(const bf16x8*)(Kc + ro + ((g ^ (l16 & 7)) << 4));
        bf16x8 kb = *(const bf16x8*)(Kc + ro + (((4 + g) ^ (l16 & 7)) << 4));
        const int kbase = ktb + kf * 16 + g * 4;
        f32x4 c0 = {0.f, 0.f, 0.f, 0.f};
        f32x4 c1 = {0.f, 0.f, 0.f, 0.f};
        __builtin_amdgcn_s_setprio(1);
        c0 = MFMA_B16(ka, q00, c0);
        c0 = MFMA_B16(kb, q01, c0);
        c1 = MFMA_B16(ka, q10, c1);
        c1 = MFMA_B16(kb, q11, c1);
        __builtin_amdgcn_s_setprio(0);
        if (dg) {
#pragma unroll
          for (int rr = 0; rr < 4; ++rr) {
            ls0 += (kbase + rr > qrow0) ? 0.f : __expf(c0[rr] * 0.125f);
            ls1 += (kbase + rr > qrow1) ? 0.f : __expf(c1[rr] * 0.125f);
          }
        } else {
          ls0 += __expf(c0[0] * 0.125f) + __expf(c0[1] * 0.125f)
               + __expf(c0[2] * 0.125f) + __expf(c0[3] * 0.125f);
          ls1 += __expf(c1[0] * 0.125f) + __expf(c1[1] * 0.125f)
               + __expf(c1[2] * 0.125f) + __expf(c1[3] * 0.125f);
        }
      }
    }
    if (kt + 1 < nktH) {
      BAR_READS_DONE();
      STAGE_WRITE(cur ^ 1);
      if (kt + 2 < nktH) STAGE_LOAD(kt + 2);
      BAR_WRITES_VISIBLE();
      cur ^= 1;
    }
  }
  ls0 += __shfl_xor(ls0, 16); ls0 += __shfl_xor(ls0, 32);
  ls1 += __shfl_xor(ls1, 16); ls1 += __shfl_xor(ls1, 32);
  if (lane < 16) {
    invl[(size_t)bh * 2048 + qrow0] = 1.f / ls0;
    invl[(size_t)bh * 2048 + qrow1] = 1.f / ls1;
  }
#undef STAGE_LOAD
#undef STAGE_WRITE
#undef BAR_READS_DONE
#undef BAR_WRITES_VISIBLE
}

// ---------- fused causal attention, v16: V staged in LDS + nt stores ----------
// R18 structure (K+V dbuf in LDS, reg-staged; in-loop zf; 96KB LDS ->
// 1 block/CU) but with NT stores restored for P-writes and zero-fill.
// Isolates: does removing V's per-wave L2 read traffic unlock nt-store BW?
__global__ __launch_bounds__(512, 2) void attn_kernel(const u16* __restrict__ Qp,
                                                      const u16* __restrict__ Kp,
                                                      const u16* __restrict__ Vt,
                                                      const float* __restrict__ invl,
                                                      float* __restrict__ attn_all,
                                                      u16* __restrict__ ctx) {
  __shared__ __align__(16) u16 Ks[2][8192];          // 2 x 16KB K tiles
  __shared__ __align__(16) u16 Vs[2][8192];          // 2 x 16KB V tiles
  __shared__ __align__(16) u16 Plds[8][16][128];     // 32KB
  const int tid = threadIdx.x;
  const int wave = tid >> 6, lane = tid & 63;
  const int g = lane >> 4, l16 = lane & 15;
  const int strip = wave >> 2;             // 0 = heavy, 1 = light
  const int pw = wave & 3;
  const int id = blockIdx.x;
  const int r8 = id >> 3;
  const int bh = (id & 7) * 4 + (r8 & 3);
  const int pair = r8 >> 2;
  const int sLo = pair, sHi = 31 - pair;
  const int b = bh >> 3, h = bh & 7;
  const int nktH = sHi / 2 + 1, nktL = sLo / 2 + 1;
  const int myNkt = strip ? nktL : nktH;
  const int myS = strip ? sLo : sHi;
  const char* KhB = (const char*)Kp + (size_t)b * 2097152 + h * 128;
  const char* VhB = (const char*)Vt + ((size_t)b * 512 + h * 64) * 4096;
  const u16* Qh = Qp + (size_t)b * 1048576 + h * 64;
  float* attn = attn_all + (size_t)bh * 4194304;
  char* KsC = (char*)Ks;
  char* VsC = (char*)Vs;
  char* Pw = (char*)&Plds[wave][0][0];
  const int swk = (l16 & 7) << 4;

  // K staging: thread t -> K row t>>2 (0..127), chunks (t&3)*2, (t&3)*2+1
  const int kr = tid >> 2;
  const int kc = (tid & 3) * 2;
  const size_t k_src = (size_t)kr * 1024 + kc * 16;
  const int k_d0 = kr * 128 + ((kc ^ (kr & 7)) << 4);
  const int k_d1 = kr * 128 + (((kc + 1) ^ (kr & 7)) << 4);
  // V staging: thread t -> V row t>>3 (0..63), chunks (t&7)*2, (t&7)*2+1
  const int vr = tid >> 3;
  const int vc = (tid & 7) * 2;
  const size_t v_src = (size_t)vr * 4096 + vc * 16;
  const int v_d0 = vr * 256 + ((vc ^ (vr & 7)) << 4);
  const int v_d1 = vr * 256 + (((vc + 1) ^ (vr & 7)) << 4);
  uint4 sk[2], sv[2];

#define STAGE_LOAD(KT)                                                         \
  { sk[0] = *(const uint4*)(KhB + (size_t)(KT) * 131072 + k_src);              \
    sk[1] = *(const uint4*)(KhB + (size_t)(KT) * 131072 + k_src + 16);         \
    sv[0] = *(const uint4*)(VhB + (size_t)(KT) * 256 + v_src);                 \
    sv[1] = *(const uint4*)(VhB + (size_t)(KT) * 256 + v_src + 16); }
#define STAGE_WRITE(CUR)                                                       \
  { *(uint4*)(KsC + (CUR) * 16384 + k_d0) = sk[0];                             \
    *(uint4*)(KsC + (CUR) * 16384 + k_d1) = sk[1];                             \
    *(uint4*)(VsC + (CUR) * 16384 + v_d0) = sv[0];                             \
    *(uint4*)(VsC + (CUR) * 16384 + v_d1) = sv[1]; }
#define BAR_READS_DONE()                                                       \
  { asm volatile("" ::: "memory");                                             \
    __builtin_amdgcn_s_barrier();                                              \
    __builtin_amdgcn_sched_barrier(0); }
#define BAR_WRITES_VISIBLE()                                                   \
  { asm volatile("s_waitcnt lgkmcnt(0)" ::: "memory");                         \
    __builtin_amdgcn_sched_barrier(0);                                         \
    __builtin_amdgcn_s_barrier();                                              \
    __builtin_amdgcn_sched_barrier(0); }

  const int qr = myS * 64 + pw * 16;
  const int qrow = qr + l16;

  bf16x8 q0 = *(const bf16x8*)(Qh + (size_t)qrow * 512 + g * 8);
  bf16x8 q1 = *(const bf16x8*)(Qh + (size_t)qrow * 512 + 32 + g * 8);
  const float inv = invl[(size_t)bh * 2048 + qrow];

  // in-loop zero-fill state
  const int z0 = myNkt * 128;
  const int vmax = ((16 - myNkt + 1) >> 1) * 16;
  const int zstep = (vmax + nktH - 1) / nktH;
  int zv = 0;
  const f32x4 z4 = {0.f, 0.f, 0.f, 0.f};

  f32x4 oacc[4] = {};
  {
    STAGE_LOAD(0); STAGE_WRITE(0);
    if (nktH > 1) STAGE_LOAD(1);
    BAR_WRITES_VISIBLE();
    int cur = 0;
    for (int kt = 0; kt < nktH; ++kt) {
      const int ktb = kt * 128;
      const bool act = (kt < myNkt);
      const bool dg = (kt == myNkt - 1);
      const char* Kc = KsC + cur * 16384;
      const char* Vc = VsC + cur * 16384;
      if (act) {
#pragma unroll
        for (int kf = 0; kf < 8; ++kf) {
          const int ro = (kf * 16 + l16) * 128;
          bf16x8 ka = *(const bf16x8*)(Kc + ro + ((g ^ (l16 & 7)) << 4));
          bf16x8 kb = *(const bf16x8*)(Kc + ro + (((4 + g) ^ (l16 & 7)) << 4));
          const int kbase = ktb + kf * 16 + g * 4;
          f32x4 c = {0.f, 0.f, 0.f, 0.f};
          __builtin_amdgcn_s_setprio(1);
          c = MFMA_B16(ka, q0, c);
          c = MFMA_B16(kb, q1, c);
          __builtin_amdgcn_s_setprio(0);
          float p[4];
#pragma unroll
          for (int r = 0; r < 4; ++r) {
            float e = __expf(c[r] * 0.125f) * inv;
            p[r] = (dg && (kbase + r > qrow)) ? 0.f : e;
          }
          unsigned lo = (unsigned)f2bf(p[0]) | ((unsigned)f2bf(p[1]) << 16);
          unsigned hi = (unsigned)f2bf(p[2]) | ((unsigned)f2bf(p[3]) << 16);
          *(uint2*)(Pw + l16 * 256 + ((kf * 32 + g * 8) ^ swk)) = make_uint2(lo, hi);
        }
        // PV from LDS V (row-XOR swizzled; 2-way = free)
#pragma unroll
        for (int kb4 = 0; kb4 < 4; ++kb4) {
          bf16x8 pa = *(const bf16x8*)(Pw + l16 * 256 + ((kb4 * 64 + g * 16) ^ swk));
#pragma unroll
          for (int cn = 0; cn < 4; ++cn) {
            const int vrow = cn * 16 + l16;
            bf16x8 vb = *(const bf16x8*)(Vc + vrow * 256 +
                                         (((kb4 * 4 + g) ^ (vrow & 7)) << 4));
            __builtin_amdgcn_s_setprio(1);
            oacc[cn] = MFMA_B16(pa, vb, oacc[cn]);
            __builtin_amdgcn_s_setprio(0);
          }
        }
        // attn nt-stores: 2 rows x 512B contiguous per instruction
        {
          const int c32 = lane & 31;
          const int rh = lane >> 5;
#pragma unroll
          for (int i = 0; i < 8; ++i) {
            const int row = i * 2 + rh;
            uint2 pk = *(const uint2*)(Pw + row * 256 + ((c32 * 8) ^ ((row & 7) << 4)));
            f32x4 o;
            o[0] = __uint_as_float(pk.x << 16);
            o[1] = __uint_as_float(pk.x & 0xffff0000u);
            o[2] = __uint_as_float(pk.y << 16);
            o[3] = __uint_as_float(pk.y & 0xffff0000u);
            __builtin_nontemporal_store(o, (f32x4*)(&attn[(size_t)(qr + row) * 2048 + ktb + c32 * 4]));
          }
        }
      }
      // in-loop zero-fill slice (nt stores)
      {
        const int zlim = (zstep * (kt + 1) < vmax) ? zstep * (kt + 1) : vmax;
        for (; zv < zlim; ++zv) {
          const int ri = zv & 15;
          const int cs = zv >> 4;
          const int col = z0 + lane * 4 + cs * 256;
          if (col < 2048)
            __builtin_nontemporal_store(
                z4, (f32x4*)(&attn[(size_t)(myS * 64 + pw + ri * 4) * 2048 + col]));
        }
      }
      if (kt + 1 < nktH) {
        BAR_READS_DONE();
        STAGE_WRITE(cur ^ 1);
        if (kt + 2 < nktH) STAGE_LOAD(kt + 2);
        BAR_WRITES_VISIBLE();
        cur ^= 1;
      }
    }
  }

  // ctx write
  u16* cb = ctx + (size_t)b * 1048576 + h * 64;
#pragma unroll
  for (int cn = 0; cn < 4; ++cn)
#pragma unroll
    for (int r = 0; r < 4; ++r)
      cb[(size_t)(qr + g * 4 + r) * 512 + cn * 16 + l16] = f2bf(oacc[cn][r]);
#undef STAGE_LOAD
#undef STAGE_WRITE
#undef BAR_READS_DONE
#undef BAR_WRITES_VISIBLE
}

// ---------- LayerNorm (residual pre-added by gemm_f32out) ----------
__global__ __launch_bounds__(256) void ln_kernel(const float* __restrict__ proj,
                                                 const float* __restrict__ gamma,
                                                 const float* __restrict__ beta,
                                                 float* __restrict__ out) {
  const int wave = threadIdx.x >> 6, lane = threadIdx.x & 63;
  const int row = blockIdx.x * 4 + wave;
  const float4* p4 = (const float4*)(proj + (size_t)row * 512);
  float4 a0 = p4[lane * 2], a1 = p4[lane * 2 + 1];
  float x[8];
  x[0] = a0.x; x[1] = a0.y; x[2] = a0.z; x[3] = a0.w;
  x[4] = a1.x; x[5] = a1.y; x[6] = a1.z; x[7] = a1.w;
  float s = 0.f;
#pragma unroll
  for (int j = 0; j < 8; ++j) s += x[j];
#pragma unroll
  for (int d = 1; d < 64; d <<= 1) s += __shfl_xor(s, d);
  float mu = s * (1.f / 512.f);
  float v = 0.f;
#pragma unroll
  for (int j = 0; j < 8; ++j) { float t = x[j] - mu; v += t * t; }
#pragma unroll
  for (int d = 1; d < 64; d <<= 1) v += __shfl_xor(v, d);
  float rs = rsqrtf(v * (1.f / 512.f) + 1e-5f);
  const float4* g4 = (const float4*)gamma;
  const float4* b4 = (const float4*)beta;
  float4 g0 = g4[lane * 2], g1 = g4[lane * 2 + 1];
  float4 bb0 = b4[lane * 2], bb1 = b4[lane * 2 + 1];
  float4 y0, y1;
  y0.x = (x[0] - mu) * rs * g0.x + bb0.x;
  y0.y = (x[1] - mu) * rs * g0.y + bb0.y;
  y0.z = (x[2] - mu) * rs * g0.z + bb0.z;
  y0.w = (x[3] - mu) * rs * g0.w + bb0.w;
  y1.x = (x[4] - mu) * rs * g1.x + bb1.x;
  y1.y = (x[5] - mu) * rs * g1.y + bb1.y;
  y1.z = (x[6] - mu) * rs * g1.z + bb1.z;
  y1.w = (x[7] - mu) * rs * g1.w + bb1.w;
  float4* o4 = (float4*)(out + (size_t)row * 512);
  o4[lane * 2] = y0;
  o4[lane * 2 + 1] = y1;
}

// ---------- launch ----------
extern "C" void kernel_launch(void* const* d_in, const int* in_sizes, int n_in,
                              void* d_out, int out_size, void* d_ws, size_t ws_size,
                              hipStream_t stream) {
  (void)in_sizes; (void)n_in; (void)out_size; (void)ws_size;
  const float* inQ = (const float*)d_in[0];
  const float* inK = (const float*)d_in[1];
  const float* inV = (const float*)d_in[2];
  const float* Wq = (const float*)d_in[4];
  const float* Wk = (const float*)d_in[5];
  const float* Wv = (const float*)d_in[6];
  const float* Wo = (const float*)d_in[7];
  const float* gamma = (const float*)d_in[8];
  const float* beta = (const float*)d_in[9];

  float* out = (float*)d_out;
  float* attn = out + (size_t)4 * 2048 * 512;

  char* ws = (char*)d_ws;
  u16* Qp  = (u16*)(ws + 0);
  u16* Kp  = (u16*)(ws + 8388608);
  u16* Vp  = (u16*)(ws + 16777216);      // freed after transpose_v -> reused for invl
  u16* Vt  = (u16*)(ws + 25165824);
  u16* ctx = (u16*)(ws + 33554432);
  u16* Wbf = (u16*)(ws + 41943040);
  float* invl = (float*)(ws + 16777216); // 256 KB, overlaps dead Vp
  float* proj = (float*)(ws + 0);        // reuses Qp+Kp after attention
  u16* Xbf = (u16*)attn;

  cvt3<<<2048, 256, 0, stream>>>(inQ, inK, inV, Xbf, 1048576, 4194304);
  cvtW<<<256, 256, 0, stream>>>(Wq, Wk, Wv, Wo, Wbf, 65536, 262144);
  gemm_qkv<<<dim3(64, 4, 3), 256, 0, stream>>>(Xbf, Wbf, Qp);
  transpose_v<<<dim3(32, 8, 4), 256, 0, stream>>>(Vp, Vt);
  lsum_kernel<<<256, 512, 0, stream>>>(Qp, Kp, invl);
  attn_kernel<<<dim3(512), 512, 0, stream>>>(Qp, Kp, Vt, invl, attn, ctx);
  gemm_f32out<<<dim3(64, 4, 1), 256, 0, stream>>>(ctx, Wbf + (size_t)3 * 262144, proj, inQ);
  ln_kernel<<<2048, 256, 0, stream>>>(proj, gamma, beta, out);
}